// Round 4
// baseline (66.039 us; speedup 1.0000x reference)
//
#include <hip/hip_runtime.h>
#include <hip/hip_bf16.h>

typedef __attribute__((ext_vector_type(8))) short short8;
typedef __attribute__((ext_vector_type(4))) float f32x4;
typedef __attribute__((ext_vector_type(4))) int   int4v;
typedef __attribute__((ext_vector_type(2))) unsigned int uint2v;

#define IN_F   4096
#define OUT_F  11008
#define KSPLIT 2
#define KHALF  (IN_F / KSPLIT)   // 2048
#define BK     64
#define NIT    (KHALF / BK)      // 32 chunks per block
#define WROW   72                // bf16 row pitch (64 + 8 pad) -> conflict-optimal reads

// f32 -> bf16 round-to-nearest-even (x path only; W ints are exact in bf16)
__device__ __forceinline__ short bf16_rne(float f) {
    unsigned u = __builtin_bit_cast(unsigned, f);
    u += 0x7FFFu + ((u >> 16) & 1u);
    return (short)(u >> 16);
}

__device__ __forceinline__ void gld16(const void* g, void* l) {
    __builtin_amdgcn_global_load_lds(
        (const __attribute__((address_space(1))) unsigned int*)g,
        (__attribute__((address_space(3))) unsigned int*)l,
        16, 0, 0);
}

// ---------- prepass 1: X f32 -> bf16 [64][4096] in d_ws ----------
__global__ __launch_bounds__(256)
void xcast(const float* __restrict__ x, unsigned short* __restrict__ xb) {
    const int i = (blockIdx.x * 256 + threadIdx.x) * 8;
    f32x4 a = *(const f32x4*)(x + i);
    f32x4 b = *(const f32x4*)(x + i + 4);
    short8 o;
#pragma unroll
    for (int j = 0; j < 4; ++j) { o[j] = bf16_rne(a[j]); o[j + 4] = bf16_rne(b[j]); }
    *(short8*)(xb + i) = o;
}

// ---------- prepass 2: out[t][o] = bias[o] (atomic accumulation base) ----------
__global__ __launch_bounds__(256)
void binit(const float* __restrict__ bias, float* __restrict__ out) {
    const unsigned cid = blockIdx.x * 256 + threadIdx.x;   // 88064 total
    const unsigned row = cid / (OUT_F / 8);
    const unsigned o   = (cid - row * (OUT_F / 8)) * 8;
    f32x4 b0 = *(const f32x4*)(bias + o);
    f32x4 b1 = *(const f32x4*)(bias + o + 4);
    float* dst = out + (size_t)row * OUT_F + o;
    *(f32x4*)dst = b0;
    *(f32x4*)(dst + 4) = b1;
}

// ---------- main kernel helpers ----------
#define GLD_W(CHUNK, SLOT) gld16(wsrc + (size_t)(CHUNK) * BK, (char*)wi[SLOT] + tid * 16)

// A(IT): two 16B fragments (kk=0,1) via asm so the compiler never emits its own
// vmcnt for them (manual counted-wait scheme owns the vmem queue).
#define ALOAD(D0, D1, IT) do {                                                   \
    const int _it = ((IT) < NIT) ? (IT) : (NIT - 1);                             \
    const char* _p = abase + (size_t)_it * 128;                                  \
    asm volatile("global_load_dwordx4 %0, %2, off\n\t"                           \
                 "global_load_dwordx4 %1, %2, off offset:64"                     \
                 : "=&v"(D0), "=&v"(D1) : "v"(_p));                              \
} while (0)

// Dequant chunk in int-slot DQS -> bf16 buffer WBW (thread owns 4 ints = 8B out)
#define DEQ(DQS, WBW) do {                                                       \
    int4v _q = *(const int4v*)((const char*)wi[DQS] + tid * 16);                 \
    unsigned _x0 = __builtin_bit_cast(unsigned, (float)(_q[0] - zp));            \
    unsigned _x1 = __builtin_bit_cast(unsigned, (float)(_q[1] - zp));            \
    unsigned _x2 = __builtin_bit_cast(unsigned, (float)(_q[2] - zp));            \
    unsigned _x3 = __builtin_bit_cast(unsigned, (float)(_q[3] - zp));            \
    uint2v _r;                                                                   \
    _r[0] = (_x0 >> 16) | (_x1 & 0xffff0000u);                                   \
    _r[1] = (_x2 >> 16) | (_x3 & 0xffff0000u);                                   \
    *(uint2v*)&wb[WBW][dqw] = _r;                                                \
} while (0)

#define MM(WBR, CUR) do {                                                        \
    short8 _b0 = *(const short8*)&wb[WBR][boff];                                 \
    short8 _b1 = *(const short8*)&wb[WBR][boff + 32];                            \
    acc = __builtin_amdgcn_mfma_f32_16x16x32_bf16(CUR##k0, _b0, acc, 0, 0, 0);   \
    acc = __builtin_amdgcn_mfma_f32_16x16x32_bf16(CUR##k1, _b1, acc, 0, 0, 0);   \
} while (0)

// One iteration. Queue invariant at the wait (issue order):
//   [W(it+1), A(it)x2, W(it+2), A(it+1)x2, W(it+3)]  -> vmcnt(4) retires
//   exactly {W(it+1), A(it)} each iteration; W stays 3 iters in flight.
#define BODY(IT, P, CUR, NX2, DQS, WBW, WBR) do {                                \
    asm volatile("s_waitcnt vmcnt(4) lgkmcnt(0)" ::: "memory");                  \
    __builtin_amdgcn_s_barrier();                                                \
    __builtin_amdgcn_sched_barrier(0);                                           \
    ALOAD(NX2##k0, NX2##k1, (IT) + 2);                                           \
    { int _c = (IT) + 4; if (_c > NIT - 1) _c = NIT - 1; GLD_W(_c, P); }         \
    DEQ(DQS, WBW);                                                               \
    MM(WBR, CUR);                                                                \
} while (0)

__global__ __launch_bounds__(256, 4)
void qlin4(const unsigned short* __restrict__ xb, const int* __restrict__ w,
           const float* __restrict__ scale_p, const int* __restrict__ zp_p,
           float* __restrict__ out)
{
    __shared__ __align__(16) int            wi[4][16 * BK];     // 16 KB int ring
    __shared__ __align__(16) unsigned short wb[2][16 * WROW];   // 4.5 KB bf16 dbuf

    const int tid  = threadIdx.x;
    const int lane = tid & 63;
    const int wv   = tid >> 6;
    const int l15  = lane & 15;
    const int lg   = lane >> 4;

    const int ob = blockIdx.x >> 1;          // output tile
    const int kh = blockIdx.x & 1;           // K half
    const int o0 = ob * 16;
    const int kb = kh * KHALF;

    const int   zp    = zp_p[0];
    const float scale = scale_p[0];

    // W staging source: thread t -> row t>>4, 16B chunk t&15 (linear, no swizzle)
    const int* wsrc = w + (size_t)(o0 + (tid >> 4)) * IN_F + kb + (tid & 15) * 4;
    // A fragment base: row = token (wv*16+l15), k = kb + lg*8 (+128B per iter)
    const char* abase = (const char*)(xb + (size_t)(wv * 16 + l15) * IN_F + kb + lg * 8);
    // dequant write index / B read offset (WROW=72 pad -> uniform bank spread)
    const int dqw  = (tid >> 4) * WROW + (tid & 15) * 4;
    const int boff = l15 * WROW + lg * 8;

    f32x4 acc = {0.f, 0.f, 0.f, 0.f};
    short8 A0k0, A0k1, A1k0, A1k1, A2k0, A2k1, A3k0, A3k1;

    // Prologue: queue = [W0, W1, A0x2, W2, A1x2, W3]
    GLD_W(0, 0);
    GLD_W(1, 1);
    ALOAD(A0k0, A0k1, 0);
    GLD_W(2, 2);
    ALOAD(A1k0, A1k1, 1);
    GLD_W(3, 3);
    asm volatile("s_waitcnt vmcnt(7)" ::: "memory");   // W0 landed
    __builtin_amdgcn_s_barrier();
    DEQ(0, 0);                                          // chunk 0 -> wb[0]

    for (int ib = 0; ib < NIT; ib += 4) {
        BODY(ib + 0, 0, A0, A2, 1, 1, 0);
        BODY(ib + 1, 1, A1, A3, 2, 0, 1);
        BODY(ib + 2, 2, A2, A0, 3, 1, 0);
        BODY(ib + 3, 3, A3, A1, 0, 0, 1);
    }

    // Epilogue: D col = lane&15, row = (lane>>4)*4 + reg (verified r1-r3)
    {
        const int o = o0 + l15;
#pragma unroll
        for (int r = 0; r < 4; ++r) {
            const int t = wv * 16 + lg * 4 + r;
            unsafeAtomicAdd(out + (size_t)t * OUT_F + o, scale * acc[r]);
        }
    }
}

extern "C" void kernel_launch(void* const* d_in, const int* in_sizes, int n_in,
                              void* d_out, int out_size, void* d_ws, size_t ws_size,
                              hipStream_t stream) {
    const float* x     = (const float*)d_in[0];
    const int*   w     = (const int*)d_in[1];
    const float* scale = (const float*)d_in[2];
    const int*   zp    = (const int*)d_in[3];
    const float* bias  = (const float*)d_in[4];
    float*       out   = (float*)d_out;
    unsigned short* xbf = (unsigned short*)d_ws;       // 512 KB of d_ws

    xcast<<<dim3(128), dim3(256), 0, stream>>>(x, xbf);
    binit<<<dim3(344), dim3(256), 0, stream>>>(bias, out);
    qlin4<<<dim3((OUT_F / 16) * KSPLIT), dim3(256), 0, stream>>>(xbf, w, scale, zp, out);
}

// Round 5
// 56.024 us; speedup vs baseline: 1.1788x; 1.1788x over previous
//
#include <hip/hip_runtime.h>
#include <hip/hip_bf16.h>

typedef __attribute__((ext_vector_type(8))) short short8;
typedef __attribute__((ext_vector_type(4))) float f32x4;
typedef __attribute__((ext_vector_type(4))) int   int4v;

#define IN_F   4096
#define OUT_F  11008
#define KSPLIT 2
#define KHALF  (IN_F / KSPLIT)   // 2048 k per block
#define BK     64
#define NIT    (KHALF / BK)      // 32 chunks
#define DEPTH  4                 // LDS ring slots; stage-ahead 3; vmcnt(6)

// f32 -> bf16 round-to-nearest-even
__device__ __forceinline__ short bf16_rne(float f) {
    unsigned u = __builtin_bit_cast(unsigned, f);
    u += 0x7FFFu + ((u >> 16) & 1u);
    return (short)(u >> 16);
}

// async global->LDS, 16B/lane; LDS dest is wave-uniform base + lane*16 (linear)
__device__ __forceinline__ void gld16(const void* g, void* l) {
    __builtin_amdgcn_global_load_lds(
        (const __attribute__((address_space(1))) unsigned int*)g,
        (__attribute__((address_space(3))) unsigned int*)l,
        16, 0, 0);
}

// ---------- prepass 1: X f32 -> bf16 [64][4096] in d_ws ----------
__global__ __launch_bounds__(256)
void xcast(const float* __restrict__ x, unsigned short* __restrict__ xb) {
    const int i = (blockIdx.x * 256 + threadIdx.x) * 8;
    f32x4 a = *(const f32x4*)(x + i);
    f32x4 b = *(const f32x4*)(x + i + 4);
    short8 o;
#pragma unroll
    for (int j = 0; j < 4; ++j) { o[j] = bf16_rne(a[j]); o[j + 4] = bf16_rne(b[j]); }
    *(short8*)(xb + i) = o;
}

// ---------- prepass 2: out[t][o] = bias[o] (base for K-split atomic adds) ----------
__global__ __launch_bounds__(256)
void binit(const float* __restrict__ bias, float* __restrict__ out) {
    const unsigned cid = blockIdx.x * 256 + threadIdx.x;   // 88064 total
    const unsigned row = cid / (OUT_F / 8);
    const unsigned o   = (cid - row * (OUT_F / 8)) * 8;
    f32x4 b0 = *(const f32x4*)(bias + o);
    f32x4 b1 = *(const f32x4*)(bias + o + 4);
    float* dst = out + (size_t)row * OUT_F + o;
    *(f32x4*)dst = b0;
    *(f32x4*)(dst + 4) = b1;
}

// ---------- main GEMM (r3 structure, deepened pipeline + K-split) ----------
// Stage chunk IT into ring slot IT&3: W 16x64 int32 (4KB, 1 gld/thr),
// X 64x64 bf16 (8KB, 2 gld/thr). Sources pre-swizzled (chunk ^ row&7),
// LDS dest linear (rule #21: swizzle both-sides-or-neither).
#define STAGE(IT) do {                                                        \
    const int _s = (IT) & (DEPTH - 1);                                        \
    gld16(wsrc + (size_t)(IT) * BK,             (char*)wt[_s] + tid * 16);    \
    gld16(xsrc + (size_t)(IT) * BK,             (char*)xt[_s] + tid * 16);    \
    gld16(xsrc + (size_t)(IT) * BK + 32 * IN_F, (char*)xt[_s] + tid * 16 + 4096); \
} while (0)

// One MFMA K-step (32 k): 2 W-reads (b128), 1 A-read (b128), dequant, MFMA.
#define KSTEP(S, KK) do {                                                     \
    const char* _wb = (const char*)wt[S] + l15 * 256;                         \
    const char* _ab = (const char*)xt[S] + (wv * 16 + l15) * 128;             \
    const int _cw = (KK) * 8 + lg * 2;                                        \
    const int _ca = (KK) * 4 + lg;                                            \
    int4v  _b0 = *(const int4v*)(_wb + (((_cw    ) ^ rswz) * 16));            \
    int4v  _b1 = *(const int4v*)(_wb + (((_cw + 1) ^ rswz) * 16));            \
    short8 _aw = *(const short8*)(_ab + ((_ca ^ rswz) * 16));                 \
    short8 _bw;                                                               \
    _Pragma("unroll")                                                         \
    for (int j = 0; j < 4; ++j) {                                             \
        float f0 = (float)(_b0[j] - zp);                                      \
        float f1 = (float)(_b1[j] - zp);                                      \
        _bw[j]     = (short)(__builtin_bit_cast(unsigned, f0) >> 16);         \
        _bw[j + 4] = (short)(__builtin_bit_cast(unsigned, f1) >> 16);         \
    }                                                                         \
    acc = __builtin_amdgcn_mfma_f32_16x16x32_bf16(_aw, _bw, acc, 0, 0, 0);    \
} while (0)

__global__ __launch_bounds__(256, 3)
void qlin5(const unsigned short* __restrict__ xb, const int* __restrict__ w,
           const float* __restrict__ scale_p, const int* __restrict__ zp_p,
           float* __restrict__ out)
{
    __shared__ __align__(16) int            wt[DEPTH][16 * BK];  // 4 x 4KB
    __shared__ __align__(16) unsigned short xt[DEPTH][64 * BK];  // 4 x 8KB (48KB -> 3 blk/CU)

    const int tid  = threadIdx.x;
    const int lane = tid & 63;
    const int wv   = tid >> 6;      // wave -> token group (16 tokens)
    const int l15  = lane & 15;
    const int lg   = lane >> 4;

    const int ob = blockIdx.x >> 1;          // output 16-col tile
    const int kh = blockIdx.x & 1;           // K half
    const int o0 = ob * 16;
    const int kb = kh * KHALF;

    const int   zp    = zp_p[0];
    const float scale = scale_p[0];

    // Staging source pointers (swizzle folded into the global address).
    const int wr = tid >> 4;                  // W row 0..15, 16B-chunk (tid&15)
    const int wc = (tid & 15) ^ (wr & 7);
    const int* wsrc = w + (size_t)(o0 + wr) * IN_F + kb + wc * 4;

    const int xr = tid >> 3;                  // X rows xr and xr+32, chunk (tid&7)
    const int xc = (tid & 7) ^ (xr & 7);
    const unsigned short* xsrc = xb + (size_t)xr * IN_F + kb + xc * 8;

    // Fragment read swizzle: A row = wv*16+l15 (row&7 == l15&7), B row = l15.
    const int rswz = l15 & 7;

    f32x4 acc = {0.f, 0.f, 0.f, 0.f};

    // Prologue: 3 chunks in flight (9 vmem instrs)
    STAGE(0);
    STAGE(1);
    STAGE(2);

    // Steady state: wait-first (chunk `it` was issued 3 iterations ago),
    // then top up the queue. Outstanding at the wait: it,it+1,it+2 = 9 instrs;
    // vmcnt(6) retires exactly chunk `it`. Never drains the queue.
    for (int it = 0; it < NIT - 2; ++it) {
        asm volatile("s_waitcnt vmcnt(6)" ::: "memory");
        __builtin_amdgcn_s_barrier();
        if (it + 3 < NIT) STAGE(it + 3);   // writes slot (it-1)&3: sealed by barrier
        const int s = it & (DEPTH - 1);
        KSTEP(s, 0);
        KSTEP(s, 1);
    }
    // Tail: two peeled iterations, progressive drain.
    asm volatile("s_waitcnt vmcnt(3)" ::: "memory");
    __builtin_amdgcn_s_barrier();
    KSTEP((NIT - 2) & (DEPTH - 1), 0);
    KSTEP((NIT - 2) & (DEPTH - 1), 1);
    asm volatile("s_waitcnt vmcnt(0)" ::: "memory");
    __builtin_amdgcn_s_barrier();
    KSTEP((NIT - 1) & (DEPTH - 1), 0);
    KSTEP((NIT - 1) & (DEPTH - 1), 1);

    // Epilogue: D col = lane&15, row = (lane>>4)*4 + reg (verified r1-r3).
    // K-split partial -> atomic add onto bias-initialized out.
    {
        const int o = o0 + l15;
#pragma unroll
        for (int r = 0; r < 4; ++r) {
            const int t = wv * 16 + lg * 4 + r;
            unsafeAtomicAdd(out + (size_t)t * OUT_F + o, scale * acc[r]);
        }
    }
}

extern "C" void kernel_launch(void* const* d_in, const int* in_sizes, int n_in,
                              void* d_out, int out_size, void* d_ws, size_t ws_size,
                              hipStream_t stream) {
    const float* x     = (const float*)d_in[0];
    const int*   w     = (const int*)d_in[1];
    const float* scale = (const float*)d_in[2];
    const int*   zp    = (const int*)d_in[3];
    const float* bias  = (const float*)d_in[4];
    float*       out   = (float*)d_out;
    unsigned short* xbf = (unsigned short*)d_ws;   // 512 KB of d_ws

    xcast<<<dim3(128), dim3(256), 0, stream>>>(x, xbf);
    binit<<<dim3(344), dim3(256), 0, stream>>>(bias, out);
    qlin5<<<dim3((OUT_F / 16) * KSPLIT), dim3(256), 0, stream>>>(xbf, w, scale, zp, out);
}

// Round 6
// 47.972 us; speedup vs baseline: 1.3766x; 1.1679x over previous
//
#include <hip/hip_runtime.h>
#include <hip/hip_bf16.h>

typedef __attribute__((ext_vector_type(8))) short short8;
typedef __attribute__((ext_vector_type(4))) float f32x4;
typedef __attribute__((ext_vector_type(4))) int   int4v;

#define IN_F   4096
#define OUT_F  11008
#define KSPLIT 4
#define KPART  (IN_F / KSPLIT)   // 1024 k per block
#define BK     64
#define NIT    (KPART / BK)      // 16 chunks
#define DEPTH  3                 // LDS ring slots; stage-ahead 2; vmcnt(6)

// f32 -> bf16 round-to-nearest-even
__device__ __forceinline__ short bf16_rne(float f) {
    unsigned u = __builtin_bit_cast(unsigned, f);
    u += 0x7FFFu + ((u >> 16) & 1u);
    return (short)(u >> 16);
}

// async global->LDS, 16B/lane; LDS dest is wave-uniform base + lane*16 (linear)
__device__ __forceinline__ void gld16(const void* g, void* l) {
    __builtin_amdgcn_global_load_lds(
        (const __attribute__((address_space(1))) unsigned int*)g,
        (__attribute__((address_space(3))) unsigned int*)l,
        16, 0, 0);
}

// dequant 8 ints -> short8 bf16 (exact: values in [-3,123], truncation lossless)
__device__ __forceinline__ short8 deq8(int4v q0, int4v q1, int zp) {
    short8 r;
#pragma unroll
    for (int j = 0; j < 4; ++j) {
        r[j]     = (short)(__builtin_bit_cast(unsigned, (float)(q0[j] - zp)) >> 16);
        r[j + 4] = (short)(__builtin_bit_cast(unsigned, (float)(q1[j] - zp)) >> 16);
    }
    return r;
}

// ---------- prepass 1: X f32 -> bf16 [64][4096] in d_ws ----------
__global__ __launch_bounds__(256)
void xcast(const float* __restrict__ x, unsigned short* __restrict__ xb) {
    const int i = (blockIdx.x * 256 + threadIdx.x) * 8;
    f32x4 a = *(const f32x4*)(x + i);
    f32x4 b = *(const f32x4*)(x + i + 4);
    short8 o;
#pragma unroll
    for (int j = 0; j < 4; ++j) { o[j] = bf16_rne(a[j]); o[j + 4] = bf16_rne(b[j]); }
    *(short8*)(xb + i) = o;
}

// ---------- prepass 2: out[t][o] = bias[o] (base for K-split atomic adds) ----------
__global__ __launch_bounds__(256)
void binit(const float* __restrict__ bias, float* __restrict__ out) {
    const unsigned cid = blockIdx.x * 256 + threadIdx.x;   // 88064 total
    const unsigned row = cid / (OUT_F / 8);
    const unsigned o   = (cid - row * (OUT_F / 8)) * 8;
    f32x4 b0 = *(const f32x4*)(bias + o);
    f32x4 b1 = *(const f32x4*)(bias + o + 4);
    float* dst = out + (size_t)row * OUT_F + o;
    *(f32x4*)dst = b0;
    *(f32x4*)(dst + 4) = b1;
}

// ---------- main GEMM: 64-col x 64-token block, 4 waves own 16-col slices ----
// Stage chunk IT into ring slot IT%3: W 64x64 int32 (16KB, 4 gld/thr),
// X 64x64 bf16 (8KB, 2 gld/thr). Sources pre-swizzled (chunk ^ row&7),
// LDS dest linear (rule #21: swizzle both-sides-or-neither).
#define STAGE(IT) do {                                                        \
    const int _s = (IT) % DEPTH;                                              \
    const int* _wsi = wsrc + (size_t)(IT) * BK;                               \
    gld16(_wsi,              (char*)wt[_s] + tid * 16);                       \
    gld16(_wsi + 16 * IN_F,  (char*)wt[_s] + 4096  + tid * 16);               \
    gld16(_wsi + 32 * IN_F,  (char*)wt[_s] + 8192  + tid * 16);               \
    gld16(_wsi + 48 * IN_F,  (char*)wt[_s] + 12288 + tid * 16);               \
    const unsigned short* _xsi = xsrc + (size_t)(IT) * BK;                    \
    gld16(_xsi,            (char*)xt[_s] + tid * 16);                         \
    gld16(_xsi + 32 * IN_F, (char*)xt[_s] + 4096 + tid * 16);                 \
} while (0)

// One chunk (BK=64): dequant own 16-col W slice once (2 k-step B-frags),
// then 4 token-groups x 2 k-steps = 8 MFMA.
#define COMPUTE(S) do {                                                       \
    const char* _wb = (const char*)wt[S] + wrow_off;                          \
    int4v _q00 = *(const int4v*)(_wb + cw00);                                 \
    int4v _q01 = *(const int4v*)(_wb + cw01);                                 \
    int4v _q10 = *(const int4v*)(_wb + cw10);                                 \
    int4v _q11 = *(const int4v*)(_wb + cw11);                                 \
    short8 _B0 = deq8(_q00, _q01, zp);                                        \
    short8 _B1 = deq8(_q10, _q11, zp);                                        \
    const char* _xb = (const char*)xt[S] + arow;                              \
    short8 _a;                                                                \
    _a = *(const short8*)(_xb +        ca0);                                  \
    acc0 = __builtin_amdgcn_mfma_f32_16x16x32_bf16(_a, _B0, acc0, 0, 0, 0);   \
    _a = *(const short8*)(_xb +        ca1);                                  \
    acc0 = __builtin_amdgcn_mfma_f32_16x16x32_bf16(_a, _B1, acc0, 0, 0, 0);   \
    _a = *(const short8*)(_xb + 2048 + ca0);                                  \
    acc1 = __builtin_amdgcn_mfma_f32_16x16x32_bf16(_a, _B0, acc1, 0, 0, 0);   \
    _a = *(const short8*)(_xb + 2048 + ca1);                                  \
    acc1 = __builtin_amdgcn_mfma_f32_16x16x32_bf16(_a, _B1, acc1, 0, 0, 0);   \
    _a = *(const short8*)(_xb + 4096 + ca0);                                  \
    acc2 = __builtin_amdgcn_mfma_f32_16x16x32_bf16(_a, _B0, acc2, 0, 0, 0);   \
    _a = *(const short8*)(_xb + 4096 + ca1);                                  \
    acc2 = __builtin_amdgcn_mfma_f32_16x16x32_bf16(_a, _B1, acc2, 0, 0, 0);   \
    _a = *(const short8*)(_xb + 6144 + ca0);                                  \
    acc3 = __builtin_amdgcn_mfma_f32_16x16x32_bf16(_a, _B0, acc3, 0, 0, 0);   \
    _a = *(const short8*)(_xb + 6144 + ca1);                                  \
    acc3 = __builtin_amdgcn_mfma_f32_16x16x32_bf16(_a, _B1, acc3, 0, 0, 0);   \
} while (0)

__global__ __launch_bounds__(256, 2)
void qlin6(const unsigned short* __restrict__ xb, const int* __restrict__ w,
           const float* __restrict__ scale_p, const int* __restrict__ zp_p,
           float* __restrict__ out)
{
    __shared__ __align__(16) int            wt[DEPTH][64 * BK];  // 3 x 16KB
    __shared__ __align__(16) unsigned short xt[DEPTH][64 * BK];  // 3 x 8KB (72KB -> 2 blk/CU)

    const int tid  = threadIdx.x;
    const int lane = tid & 63;
    const int wv   = tid >> 6;      // wave -> 16-col slice of the 64-col tile
    const int l15  = lane & 15;
    const int lg   = lane >> 4;

    const int ob = blockIdx.x >> 2;          // output 64-col tile (172 tiles)
    const int kh = blockIdx.x & 3;           // K quarter
    const int o0 = ob * 64;
    const int kb = kh * KPART;

    const int   zp    = zp_p[0];
    const float scale = scale_p[0];

    // W staging source: thread t -> row t>>4 (+16q), 16B chunk (t&15)^(row&7).
    // (row+16q)&7 == row&7, so one swizzled base serves all 4 q-slices.
    const int wr = tid >> 4;
    const int wc = (tid & 15) ^ (wr & 7);
    const int* wsrc = w + (size_t)(o0 + wr) * IN_F + kb + wc * 4;

    // X staging source: rows xr and xr+32, chunk (t&7)^(xr&7).
    const int xr = tid >> 3;
    const int xc = (tid & 7) ^ (xr & 7);
    const unsigned short* xsrc = xb + (size_t)xr * IN_F + kb + xc * 8;

    // Read-side swizzle: B row = wv*16+l15, A row = g*16+l15; both &7 == l15&7.
    const int rswz = l15 & 7;
    const int wrow_off = (wv * 16 + l15) * 256;          // W LDS row (256B pitch)
    const int cw00 = ((lg * 2    ) ^ rswz) * 16;         // k-step 0 chunks
    const int cw01 = ((lg * 2 + 1) ^ rswz) * 16;
    const int cw10 = ((8 + lg * 2    ) ^ rswz) * 16;     // k-step 1 chunks
    const int cw11 = ((8 + lg * 2 + 1) ^ rswz) * 16;
    const int arow = l15 * 128;                          // X LDS row (128B pitch)
    const int ca0  = ((lg    ) ^ rswz) * 16;
    const int ca1  = ((4 + lg) ^ rswz) * 16;

    f32x4 acc0 = {0.f, 0.f, 0.f, 0.f};
    f32x4 acc1 = {0.f, 0.f, 0.f, 0.f};
    f32x4 acc2 = {0.f, 0.f, 0.f, 0.f};
    f32x4 acc3 = {0.f, 0.f, 0.f, 0.f};

    // Prologue: 2 chunks in flight (12 vmem instrs)
    STAGE(0);
    STAGE(1);

    // Steady state: wait-first (chunk `it` issued 2 iterations ago),
    // vmcnt(6) retires exactly chunk `it`, chunk it+1 stays in flight.
    // STAGE(it+2) reuses the slot read at it-1, sealed by this barrier.
#pragma unroll 3
    for (int it = 0; it < NIT - 1; ++it) {
        asm volatile("s_waitcnt vmcnt(6)" ::: "memory");
        __builtin_amdgcn_s_barrier();
        if (it + 2 < NIT) STAGE(it + 2);
        COMPUTE(it % DEPTH);
    }
    asm volatile("s_waitcnt vmcnt(0)" ::: "memory");
    __builtin_amdgcn_s_barrier();
    COMPUTE((NIT - 1) % DEPTH);

    // Epilogue: D col = lane&15 (out col), row = (lane>>4)*4 + reg (token).
    // K-split partial -> atomic add onto bias-initialized out.
    {
        const int o = o0 + wv * 16 + l15;
        float* op = out + o;
#pragma unroll
        for (int r = 0; r < 4; ++r) {
            const int tr = lg * 4 + r;
            unsafeAtomicAdd(op + (size_t)(tr     ) * OUT_F, scale * acc0[r]);
            unsafeAtomicAdd(op + (size_t)(tr + 16) * OUT_F, scale * acc1[r]);
            unsafeAtomicAdd(op + (size_t)(tr + 32) * OUT_F, scale * acc2[r]);
            unsafeAtomicAdd(op + (size_t)(tr + 48) * OUT_F, scale * acc3[r]);
        }
    }
}

extern "C" void kernel_launch(void* const* d_in, const int* in_sizes, int n_in,
                              void* d_out, int out_size, void* d_ws, size_t ws_size,
                              hipStream_t stream) {
    const float* x     = (const float*)d_in[0];
    const int*   w     = (const int*)d_in[1];
    const float* scale = (const float*)d_in[2];
    const int*   zp    = (const int*)d_in[3];
    const float* bias  = (const float*)d_in[4];
    float*       out   = (float*)d_out;
    unsigned short* xbf = (unsigned short*)d_ws;   // 512 KB of d_ws

    xcast<<<dim3(128), dim3(256), 0, stream>>>(x, xbf);
    binit<<<dim3(344), dim3(256), 0, stream>>>(bias, out);
    qlin6<<<dim3((OUT_F / 64) * KSPLIT), dim3(256), 0, stream>>>(xbf, w, scale, zp, out);
}